// Round 1
// 443.395 us; speedup vs baseline: 1.0315x; 1.0315x over previous
//
#include <hip/hip_runtime.h>
#include <hip/hip_bf16.h>

// B=16, S=2048, D=1024, OUT=1024.
// attn[b,s] = softmax_s( sum_o v[o]*relu( [hidden|c_t|enc].W[o,:] + bias[o] ) )
// c_t term hoisted to cbias[b,o]; main GEMM: A[32768,2048](bf16) x W_he[1024,2048](bf16).
// R3: BK=64 XOR swizzle -> 0 conflicts. R6: 256x128 2-barrier loop = 160us (859 TF,
// MfmaUtil 37% = m97-structure ceiling). R7: port to 256x256 8-phase schedule
// (T3+T4 counted vmcnt + T5 setprio, raw s_barrier, double-buffered 128KiB LDS).

typedef __attribute__((ext_vector_type(8))) short short8;
typedef __attribute__((ext_vector_type(4))) float f32x4;
typedef __attribute__((ext_vector_type(8))) unsigned short ushort8v;
typedef __attribute__((ext_vector_type(4))) unsigned short ushort4v;

#define NB 16
#define NS 2048
#define ND 1024
#define NOUT 1024
#define NM (NB * NS)   // 32768 rows
#define KHE 2048       // hidden+encoder K

// 8-phase GEMM tile geometry
#define B8M 256
#define B8N 256
#define B8K 64
#define NT8 (KHE / B8K)   // 32 K-tiles

// prep_k block ranges
#define PREP_ACONV 16384
#define PREP_WCONV 2048
#define PREP_CBIAS 256
#define PREP_ZERO 32

__device__ __forceinline__ unsigned short bf16_rne(float x) {
    unsigned int u = __float_as_uint(x);
    unsigned int r = (u + 0x7fffu + ((u >> 16) & 1u)) >> 16;
    return (unsigned short)r;
}

__device__ __forceinline__ void gload_lds16(const unsigned short* g, unsigned short* l) {
    __builtin_amdgcn_global_load_lds(
        (const __attribute__((address_space(1))) void*)g,
        (__attribute__((address_space(3))) void*)l, 16, 0, 0);
}

// raw barrier with compiler memory fences: keeps LDS/global ops from migrating across,
// but does NOT drain vmcnt (the whole point vs __syncthreads()).
__device__ __forceinline__ void bar_fence() {
    asm volatile("" ::: "memory");
    __builtin_amdgcn_s_barrier();
    asm volatile("" ::: "memory");
}

// ---------- fused prep: A-convert | W-convert | cbias | zero-logits ----------------------
__global__ __launch_bounds__(256) void prep_k(const float* __restrict__ hidden,
                                              const float* __restrict__ enc,
                                              const float* __restrict__ c_t,
                                              const float* __restrict__ W,
                                              const float* __restrict__ bias,
                                              unsigned short* __restrict__ Abf,
                                              unsigned short* __restrict__ Wbf,
                                              float* __restrict__ cbias,
                                              float* __restrict__ logits) {
    const int bid = blockIdx.x;
    const int tid = threadIdx.x;
    if (bid < PREP_ACONV) {
        size_t c = (size_t)bid * 256 + tid;
        size_t m = c >> 7;
        int k = (int)(c & 127) * 16;
        const float* src = (k < ND) ? (hidden + m * ND + k) : (enc + m * ND + (k - ND));
        float4 f0 = ((const float4*)src)[0];
        float4 f1 = ((const float4*)src)[1];
        float4 f2 = ((const float4*)src)[2];
        float4 f3 = ((const float4*)src)[3];
        ushort8v h0, h1;
        h0[0] = bf16_rne(f0.x); h0[1] = bf16_rne(f0.y); h0[2] = bf16_rne(f0.z); h0[3] = bf16_rne(f0.w);
        h0[4] = bf16_rne(f1.x); h0[5] = bf16_rne(f1.y); h0[6] = bf16_rne(f1.z); h0[7] = bf16_rne(f1.w);
        h1[0] = bf16_rne(f2.x); h1[1] = bf16_rne(f2.y); h1[2] = bf16_rne(f2.z); h1[3] = bf16_rne(f2.w);
        h1[4] = bf16_rne(f3.x); h1[5] = bf16_rne(f3.y); h1[6] = bf16_rne(f3.z); h1[7] = bf16_rne(f3.w);
        *(ushort8v*)(Abf + m * KHE + k) = h0;
        *(ushort8v*)(Abf + m * KHE + k + 8) = h1;
    } else if (bid < PREP_ACONV + PREP_WCONV) {
        int idx = (bid - PREP_ACONV) * 256 + tid;
        int o = idx >> 9;
        int k = (idx & 511) * 4;
        int off = (k < ND) ? k : (k + ND);
        float4 f = *(const float4*)(W + (size_t)o * 3072 + off);
        ushort4v h;
        h.x = bf16_rne(f.x); h.y = bf16_rne(f.y); h.z = bf16_rne(f.z); h.w = bf16_rne(f.w);
        *(ushort4v*)(Wbf + (size_t)o * KHE + k) = h;
    } else if (bid < PREP_ACONV + PREP_WCONV + PREP_CBIAS) {
        int o = (bid - PREP_ACONV - PREP_WCONV) * 4 + (tid >> 6);
        int lane = tid & 63;
        const float* w = W + (size_t)o * 3072 + ND;
        float wr[16];
        #pragma unroll
        for (int j = 0; j < 16; ++j) wr[j] = w[lane + j * 64];
        float bo = bias[o];
        for (int b = 0; b < NB; ++b) {
            const float* cc = c_t + (size_t)b * ND;
            float s = 0.f;
            #pragma unroll
            for (int j = 0; j < 16; ++j) s = fmaf(cc[lane + j * 64], wr[j], s);
            #pragma unroll
            for (int m = 1; m < 64; m <<= 1) s += __shfl_xor(s, m);
            if (lane == 0) cbias[b * NOUT + o] = s + bo;
        }
    } else {
        int idx = (bid - PREP_ACONV - PREP_WCONV - PREP_CBIAS) * 256 + tid;
        ((float4*)logits)[idx] = make_float4(0.f, 0.f, 0.f, 0.f);
    }
}

// ---------- standalone prep pieces (ws-fallback path only) -------------------------------
__global__ __launch_bounds__(256) void wconv_k(const float* __restrict__ W,
                                               unsigned short* __restrict__ Wbf) {
    int idx = blockIdx.x * 256 + threadIdx.x;
    int o = idx >> 9;
    int k = (idx & 511) * 4;
    int off = (k < ND) ? k : (k + ND);
    float4 f = *(const float4*)(W + (size_t)o * 3072 + off);
    ushort4v h;
    h.x = bf16_rne(f.x); h.y = bf16_rne(f.y); h.z = bf16_rne(f.z); h.w = bf16_rne(f.w);
    *(ushort4v*)(Wbf + (size_t)o * KHE + k) = h;
}

__global__ __launch_bounds__(256) void cbias_k(const float* __restrict__ c_t,
                                               const float* __restrict__ W,
                                               const float* __restrict__ bias,
                                               float* __restrict__ cbias) {
    int o = blockIdx.x * 4 + (threadIdx.x >> 6);
    int lane = threadIdx.x & 63;
    const float* w = W + (size_t)o * 3072 + ND;
    float wr[16];
    #pragma unroll
    for (int j = 0; j < 16; ++j) wr[j] = w[lane + j * 64];
    float bo = bias[o];
    for (int b = 0; b < NB; ++b) {
        const float* c = c_t + (size_t)b * ND;
        float s = 0.f;
        #pragma unroll
        for (int j = 0; j < 16; ++j) s = fmaf(c[lane + j * 64], wr[j], s);
        #pragma unroll
        for (int m = 1; m < 64; m <<= 1) s += __shfl_xor(s, m);
        if (lane == 0) cbias[b * NOUT + o] = s + bo;
    }
}

// ---------- 8-phase GEMM: 256x256, 8 waves (2M x 4N), BK=64, double-buffered LDS ---------
// Schedule per K-tile (quads = (mh,nh) over each wave's 128x64 C):
//   ph0: ds_read A-alpha + B-alpha (12xb128) | stage A-alpha' -> buf^1 | bar | 16 MFMA (0,0) | bar
//   ph1: ds_read B-beta  ( 4xb128)           | stage B-alpha'          | bar | 16 MFMA (0,1) | vmcnt(4) bar
//   ph2: ds_read A-beta  ( 8xb128)           | stage B-beta'           | bar | 16 MFMA (1,1) | bar
//   ph3: ds_read B-alpha ( 4xb128, re-read)  | stage A-beta'           | bar | 16 MFMA (1,0) | vmcnt(2) bar
// "alpha" halves = the block rows read by quads *h=0 across both/all waves:
//   A-alpha = rows [0,64)+[128,192); B-alpha = rows r with (r>>5)&1==0.
// Counted vmcnt placed BEFORE the closing barrier => all waves' covered loads have landed
// before any wave reaches the ds_read that consumes them (>=2-phase issue->read lag).
// Last tile: no prefetch => outstanding count shrinks, so ph1 uses vmcnt(0) there.
// LDS swizzle (verified 0-conflict R3/R5): slot s of row r holds global 16B-chunk s^(r&7);
// staging pre-swizzles the per-lane GLOBAL address, LDS dest stays linear (rule 21).
__global__ __launch_bounds__(512, 2) void gemm8_k(const unsigned short* __restrict__ Abf,
                                                  const unsigned short* __restrict__ Wbf,
                                                  const float* __restrict__ cbias,
                                                  const float* __restrict__ v,
                                                  float* __restrict__ logits) {
    __shared__ unsigned short Ls[2][512][B8K] __attribute__((aligned(16)));  // 128 KiB
    __shared__ float rowsum[4][B8M];   // 4 KiB
    __shared__ float cb_s[B8N];
    __shared__ float v_s[B8N];

    const int tid = threadIdx.x;
    const int ntile = blockIdx.x & 3;      // 4 ntiles
    const int mtile = blockIdx.x >> 2;     // 128 mtiles
    const int m0 = mtile * B8M;            // 2048 % 256 == 0 -> no batch straddle
    const int o0 = ntile * B8N;
    const int batch = m0 >> 11;

    if (tid < B8N) {
        cb_s[tid] = cbias[batch * NOUT + o0 + tid];
        v_s[tid] = v[o0 + tid];
    }

    const int wid = tid >> 6;        // 0..7
    const int lane = tid & 63;
    const int wm = (wid & 1) * 128;  // 2 m-waves (per-wave C = 128x64)
    const int wn = (wid >> 1) * 64;  // 4 n-waves
    const int lr = lane >> 3;              // staging row-in-8
    const int lc = (lane & 7) ^ lr;        // pre-swizzled source 16B chunk

    f32x4 acc[8][4] = {};
    short8 a[4][2], b[2][2];

    auto stageA = [&](int buf, int kt, int h) {
        #pragma unroll
        for (int t = 0; t < 2; ++t) {
            const int r0 = t * 128 + h * 64 + wid * 8;  // 8-aligned
            gload_lds16(Abf + (size_t)(m0 + r0 + lr) * KHE + kt + lc * 8, &Ls[buf][r0][0]);
        }
    };
    auto stageB = [&](int buf, int kt, int h) {
        #pragma unroll
        for (int t = 0; t < 2; ++t) {
            const int r0 = (wid >> 1) * 64 + h * 32 + (wid & 1) * 8 + t * 16;  // 8-aligned
            gload_lds16(Wbf + (size_t)(o0 + r0 + lr) * KHE + kt + lc * 8, &Ls[buf][256 + r0][0]);
        }
    };
    auto loadA = [&](int buf, int mh) {
        #pragma unroll
        for (int ks = 0; ks < 2; ++ks) {
            const int cb = ks * 4 + (lane >> 4);
            #pragma unroll
            for (int i = 0; i < 4; ++i) {
                const int row = wm + mh * 64 + i * 16 + (lane & 15);
                a[i][ks] = *(const short8*)&Ls[buf][row][(cb ^ (row & 7)) * 8];
            }
        }
    };
    auto loadB = [&](int buf, int nh) {
        #pragma unroll
        for (int ks = 0; ks < 2; ++ks) {
            const int cb = ks * 4 + (lane >> 4);
            #pragma unroll
            for (int j = 0; j < 2; ++j) {
                const int row = wn + nh * 32 + j * 16 + (lane & 15);
                b[j][ks] = *(const short8*)&Ls[buf][256 + row][(cb ^ (row & 7)) * 8];
            }
        }
    };
    auto mfma16 = [&](int mh, int nh) {
        __builtin_amdgcn_s_setprio(1);
        #pragma unroll
        for (int ks = 0; ks < 2; ++ks)
            #pragma unroll
            for (int i = 0; i < 4; ++i)
                #pragma unroll
                for (int j = 0; j < 2; ++j)
                    acc[mh * 4 + i][nh * 2 + j] = __builtin_amdgcn_mfma_f32_16x16x32_bf16(
                        a[i][ks], b[j][ks], acc[mh * 4 + i][nh * 2 + j], 0, 0, 0);
        __builtin_amdgcn_s_setprio(0);
    };

    // prologue: tile0 -> buf0, issue order A-alpha, B-alpha, B-beta, A-beta (8 loads).
    // vmcnt(2): lands the first three halves; A-beta stays in flight (read at ph2,
    // covered by ph1's vmcnt(4)).
    stageA(0, 0, 0);
    stageB(0, 0, 0);
    stageB(0, 0, 1);
    stageA(0, 0, 1);
    asm volatile("s_waitcnt vmcnt(2)" ::: "memory");
    __builtin_amdgcn_s_barrier();
    asm volatile("" ::: "memory");

    #pragma unroll 2
    for (int t = 0; t < NT8; ++t) {
        const int cur = t & 1, nxt = cur ^ 1;
        const int kt1 = (t + 1) * B8K;
        const bool pf = (t + 1 < NT8);

        // phase 0
        loadA(cur, 0);
        loadB(cur, 0);
        if (pf) stageA(nxt, kt1, 0);
        bar_fence();
        mfma16(0, 0);
        bar_fence();

        // phase 1
        loadB(cur, 1);
        if (pf) stageB(nxt, kt1, 0);
        bar_fence();
        mfma16(0, 1);
        if (pf) asm volatile("s_waitcnt vmcnt(4)" ::: "memory");  // lands A-beta(t)
        else    asm volatile("s_waitcnt vmcnt(0)" ::: "memory");  // tail: fewer outstanding
        bar_fence();

        // phase 2
        loadA(cur, 1);
        if (pf) stageB(nxt, kt1, 1);
        bar_fence();
        mfma16(1, 1);
        bar_fence();

        // phase 3
        loadB(cur, 0);                 // re-read B-alpha (still resident)
        if (pf) stageA(nxt, kt1, 1);
        bar_fence();
        mfma16(1, 0);
        asm volatile("s_waitcnt vmcnt(2)" ::: "memory");  // lands A-alpha',B-alpha',B-beta'
        bar_fence();
    }

    __syncthreads();  // full drain before epilogue

    // epilogue: relu(acc + cbias) * v, reduce over this block's 256 o's.
    // C/D: col = lane&15 (o), row = (lane>>4)*4 + reg (m).  (verified rounds 1-6)
    const int col = lane & 15;
    const int q = lane >> 4;
    float vv[4], cbv[4];
    #pragma unroll
    for (int j = 0; j < 4; ++j) {
        const int oc = wn + j * 16 + col;
        vv[j] = v_s[oc];
        cbv[j] = cb_s[oc];
    }
    #pragma unroll
    for (int i = 0; i < 8; ++i) {
        #pragma unroll
        for (int r = 0; r < 4; ++r) {
            float s = 0.f;
            #pragma unroll
            for (int j = 0; j < 4; ++j) {
                float e = acc[i][j][r] + cbv[j];
                e = fmaxf(e, 0.f);
                s = fmaf(e, vv[j], s);
            }
            s += __shfl_xor(s, 1);
            s += __shfl_xor(s, 2);
            s += __shfl_xor(s, 4);
            s += __shfl_xor(s, 8);
            if (col == 0) rowsum[wid >> 1][wm + i * 16 + q * 4 + r] = s;
        }
    }
    __syncthreads();
    if (tid < B8M)
        atomicAdd(&logits[m0 + tid],
                  rowsum[0][tid] + rowsum[1][tid] + rowsum[2][tid] + rowsum[3][tid]);
}

// ---------- fallback GEMM (fp32 A staged+converted in-kernel, 128x128, BK=32) ------------
__global__ __launch_bounds__(256) void gemm_att_k(const float* __restrict__ hidden,
                                                  const float* __restrict__ enc,
                                                  const unsigned short* __restrict__ Wbf,
                                                  const float* __restrict__ Wf,
                                                  const float* __restrict__ cbias,
                                                  const float* __restrict__ v,
                                                  float* __restrict__ logits,
                                                  int use_wbf) {
    __shared__ unsigned short As[128 * 32] __attribute__((aligned(16)));
    __shared__ unsigned short Bs[128 * 32] __attribute__((aligned(16)));
    __shared__ float rowsum[2][128];
    __shared__ float cb_s[128];
    __shared__ float v_s[128];

    const int tid = threadIdx.x;
    const int ntile = blockIdx.x & 7;
    const int mtile = blockIdx.x >> 3;
    const int m0 = mtile * 128;
    const int o0 = ntile * 128;
    const int batch = m0 >> 11;

    if (tid < 128) {
        cb_s[tid] = cbias[batch * NOUT + o0 + tid];
        v_s[tid] = v[o0 + tid];
    }

    const int wid = tid >> 6;
    const int lane = tid & 63;
    const int wm = (wid & 1) * 64;
    const int wn = (wid >> 1) * 64;

    f32x4 acc[4][4] = {};

    for (int kt = 0; kt < KHE; kt += 32) {
        const float* Abase = (kt < ND) ? hidden : enc;
        const int aoff = (kt < ND) ? kt : (kt - ND);
        #pragma unroll
        for (int i = 0; i < 4; ++i) {
            int p = tid + i * 256;
            int row = p >> 3, kc = p & 7;
            float4 f = *(const float4*)(Abase + (size_t)(m0 + row) * ND + aoff + kc * 4);
            ushort4v h;
            h.x = bf16_rne(f.x); h.y = bf16_rne(f.y); h.z = bf16_rne(f.z); h.w = bf16_rne(f.w);
            *(ushort4v*)(As + row * 32 + kc * 4) = h;
        }
        if (use_wbf) {
            #pragma unroll
            for (int i = 0; i < 2; ++i) {
                int u = tid + i * 256;
                int ol = u >> 2, kc = u & 3;
                ushort8v w8 = *(const ushort8v*)(Wbf + (size_t)(o0 + ol) * KHE + kt + kc * 8);
                *(ushort8v*)(Bs + ol * 32 + kc * 8) = w8;
            }
        } else {
            const int woff = (kt < ND) ? kt : (kt + ND);
            #pragma unroll
            for (int i = 0; i < 4; ++i) {
                int p = tid + i * 256;
                int row = p >> 3, kc = p & 7;
                float4 f = *(const float4*)(Wf + (size_t)(o0 + row) * 3072 + woff + kc * 4);
                ushort4v h;
                h.x = bf16_rne(f.x); h.y = bf16_rne(f.y); h.z = bf16_rne(f.z); h.w = bf16_rne(f.w);
                *(ushort4v*)(Bs + row * 32 + kc * 4) = h;
            }
        }
        __syncthreads();

        short8 a_frag[4], b_frag[4];
        #pragma unroll
        for (int i = 0; i < 4; ++i)
            a_frag[i] = *(const short8*)(As + (wm + i * 16 + (lane & 15)) * 32 + (lane >> 4) * 8);
        #pragma unroll
        for (int j = 0; j < 4; ++j)
            b_frag[j] = *(const short8*)(Bs + (wn + j * 16 + (lane & 15)) * 32 + (lane >> 4) * 8);
        #pragma unroll
        for (int i = 0; i < 4; ++i)
            #pragma unroll
            for (int j = 0; j < 4; ++j)
                acc[i][j] = __builtin_amdgcn_mfma_f32_16x16x32_bf16(a_frag[i], b_frag[j],
                                                                    acc[i][j], 0, 0, 0);
        __syncthreads();
    }

    const int col = lane & 15;
    const int q = lane >> 4;
    float vv[4], cbv[4];
    #pragma unroll
    for (int j = 0; j < 4; ++j) {
        int oc = wn + j * 16 + col;
        vv[j] = v_s[oc];
        cbv[j] = cb_s[oc];
    }
    #pragma unroll
    for (int i = 0; i < 4; ++i) {
        #pragma unroll
        for (int r = 0; r < 4; ++r) {
            float s = 0.f;
            #pragma unroll
            for (int j = 0; j < 4; ++j) {
                float e = acc[i][j][r] + cbv[j];
                e = fmaxf(e, 0.f);
                s = fmaf(e, vv[j], s);
            }
            s += __shfl_xor(s, 1);
            s += __shfl_xor(s, 2);
            s += __shfl_xor(s, 4);
            s += __shfl_xor(s, 8);
            if (col == 0) rowsum[wid >> 1][wm + i * 16 + q * 4 + r] = s;
        }
    }
    __syncthreads();
    if (tid < 128) atomicAdd(&logits[m0 + tid], rowsum[0][tid] + rowsum[1][tid]);
}

// ---------- softmax over S per batch -----------------------------------------------------
__global__ __launch_bounds__(256) void softmax_k(const float* __restrict__ logits,
                                                 float* __restrict__ out) {
    const int b = blockIdx.x;
    const int tid = threadIdx.x;
    const int lane = tid & 63, wid = tid >> 6;
    __shared__ float redmax[4];
    __shared__ float redsum[4];
    const float* L = logits + (size_t)b * NS;
    float x[8];
    float mx = -3.4e38f;
    #pragma unroll
    for (int i = 0; i < 8; ++i) {
        x[i] = L[tid + i * 256];
        mx = fmaxf(mx, x[i]);
    }
    #pragma unroll
    for (int m = 1; m < 64; m <<= 1) mx = fmaxf(mx, __shfl_xor(mx, m));
    if (lane == 0) redmax[wid] = mx;
    __syncthreads();
    mx = fmaxf(fmaxf(redmax[0], redmax[1]), fmaxf(redmax[2], redmax[3]));
    float sum = 0.f;
    #pragma unroll
    for (int i = 0; i < 8; ++i) {
        x[i] = expf(x[i] - mx);
        sum += x[i];
    }
    #pragma unroll
    for (int m = 1; m < 64; m <<= 1) sum += __shfl_xor(sum, m);
    if (lane == 0) redsum[wid] = sum;
    __syncthreads();
    float inv = 1.0f / (redsum[0] + redsum[1] + redsum[2] + redsum[3]);
    #pragma unroll
    for (int i = 0; i < 8; ++i) out[(size_t)b * NS + tid + i * 256] = x[i] * inv;
}

extern "C" void kernel_launch(void* const* d_in, const int* in_sizes, int n_in,
                              void* d_out, int out_size, void* d_ws, size_t ws_size,
                              hipStream_t stream) {
    const float* hidden = (const float*)d_in[0];
    const float* enc    = (const float*)d_in[1];
    const float* c_t    = (const float*)d_in[2];
    const float* W      = (const float*)d_in[3];
    const float* bias   = (const float*)d_in[4];
    const float* v      = (const float*)d_in[5];
    float* out = (float*)d_out;

    char* ws = (char*)d_ws;
    float* logits = (float*)ws;                             // 131072 B
    float* cbias  = (float*)(ws + 131072);                  //  65536 B
    unsigned short* Wbf = (unsigned short*)(ws + 196608);   // 4 MiB
    unsigned short* Abf = (unsigned short*)(ws + 196608 + 4194304);  // 128 MiB
    const size_t need_wbf = 196608 + (size_t)NOUT * KHE * 2;
    const size_t need_abf = need_wbf + (size_t)NM * KHE * 2;

    if (ws_size >= need_abf) {
        prep_k<<<PREP_ACONV + PREP_WCONV + PREP_CBIAS + PREP_ZERO, 256, 0, stream>>>(
            hidden, enc, c_t, W, bias, Abf, Wbf, cbias, logits);
        gemm8_k<<<(NM / B8M) * (NOUT / B8N), 512, 0, stream>>>(Abf, Wbf, cbias, v, logits);
    } else if (ws_size >= need_wbf) {
        hipMemsetAsync(logits, 0, NM * sizeof(float), stream);
        cbias_k<<<NOUT / 4, 256, 0, stream>>>(c_t, W, bias, cbias);
        wconv_k<<<(NOUT * KHE / 4) / 256, 256, 0, stream>>>(W, Wbf);
        gemm_att_k<<<(NM / 128) * (NOUT / 128), 256, 0, stream>>>(hidden, enc, Wbf, W, cbias, v,
                                                                  logits, 1);
    } else {
        hipMemsetAsync(logits, 0, NM * sizeof(float), stream);
        cbias_k<<<NOUT / 4, 256, 0, stream>>>(c_t, W, bias, cbias);
        gemm_att_k<<<(NM / 128) * (NOUT / 128), 256, 0, stream>>>(hidden, enc, Wbf, W, cbias, v,
                                                                  logits, 0);
    }
    softmax_k<<<NB, 256, 0, stream>>>(logits, out);
}

// Round 2
// 426.609 us; speedup vs baseline: 1.0721x; 1.0393x over previous
//
#include <hip/hip_runtime.h>
#include <hip/hip_bf16.h>

// B=16, S=2048, D=1024, OUT=1024.
// attn[b,s] = softmax_s( sum_o v[o]*relu( [hidden|c_t|enc].W[o,:] + bias[o] ) )
// c_t term hoisted to cbias[b,o]; main GEMM: A[32768,2048](bf16) x W_he[1024,2048](bf16).
// R3: BK=64 XOR swizzle -> 0 conflicts. R6: 256x128 2-barrier = 160us (MfmaUtil 37%).
// R7: 8-phase lockstep barriers = 151us, MfmaUtil STILL 37.7% -- post-mortem: phase =
// sync + LDS-drain (857cy) + MFMA (515cy) fully SERIALIZED by the barrier pairs.
// R8: one barrier per K-tile, free-running waves, snake-order reads pipelined 1-3
// sub-phases ahead (24 ds_read/wave/tile, the minimum), reg-staging (global->VGPR at
// tile start, ds_write in back half) so reads and writes never alias-stall.

typedef __attribute__((ext_vector_type(8))) short short8;
typedef __attribute__((ext_vector_type(4))) float f32x4;
typedef __attribute__((ext_vector_type(8))) unsigned short ushort8v;
typedef __attribute__((ext_vector_type(4))) unsigned short ushort4v;

#define NB 16
#define NS 2048
#define ND 1024
#define NOUT 1024
#define NM (NB * NS)   // 32768 rows
#define KHE 2048       // hidden+encoder K

// GEMM tile geometry
#define B8M 256
#define B8N 256
#define B8K 64
#define NT8 (KHE / B8K)   // 32 K-tiles

// prep_k block ranges
#define PREP_ACONV 16384
#define PREP_WCONV 2048
#define PREP_CBIAS 256
#define PREP_ZERO 32

__device__ __forceinline__ unsigned short bf16_rne(float x) {
    unsigned int u = __float_as_uint(x);
    unsigned int r = (u + 0x7fffu + ((u >> 16) & 1u)) >> 16;
    return (unsigned short)r;
}

// ---------- fused prep: A-convert | W-convert | cbias | zero-logits ----------------------
__global__ __launch_bounds__(256) void prep_k(const float* __restrict__ hidden,
                                              const float* __restrict__ enc,
                                              const float* __restrict__ c_t,
                                              const float* __restrict__ W,
                                              const float* __restrict__ bias,
                                              unsigned short* __restrict__ Abf,
                                              unsigned short* __restrict__ Wbf,
                                              float* __restrict__ cbias,
                                              float* __restrict__ logits) {
    const int bid = blockIdx.x;
    const int tid = threadIdx.x;
    if (bid < PREP_ACONV) {
        size_t c = (size_t)bid * 256 + tid;
        size_t m = c >> 7;
        int k = (int)(c & 127) * 16;
        const float* src = (k < ND) ? (hidden + m * ND + k) : (enc + m * ND + (k - ND));
        float4 f0 = ((const float4*)src)[0];
        float4 f1 = ((const float4*)src)[1];
        float4 f2 = ((const float4*)src)[2];
        float4 f3 = ((const float4*)src)[3];
        ushort8v h0, h1;
        h0[0] = bf16_rne(f0.x); h0[1] = bf16_rne(f0.y); h0[2] = bf16_rne(f0.z); h0[3] = bf16_rne(f0.w);
        h0[4] = bf16_rne(f1.x); h0[5] = bf16_rne(f1.y); h0[6] = bf16_rne(f1.z); h0[7] = bf16_rne(f1.w);
        h1[0] = bf16_rne(f2.x); h1[1] = bf16_rne(f2.y); h1[2] = bf16_rne(f2.z); h1[3] = bf16_rne(f2.w);
        h1[4] = bf16_rne(f3.x); h1[5] = bf16_rne(f3.y); h1[6] = bf16_rne(f3.z); h1[7] = bf16_rne(f3.w);
        *(ushort8v*)(Abf + m * KHE + k) = h0;
        *(ushort8v*)(Abf + m * KHE + k + 8) = h1;
    } else if (bid < PREP_ACONV + PREP_WCONV) {
        int idx = (bid - PREP_ACONV) * 256 + tid;
        int o = idx >> 9;
        int k = (idx & 511) * 4;
        int off = (k < ND) ? k : (k + ND);
        float4 f = *(const float4*)(W + (size_t)o * 3072 + off);
        ushort4v h;
        h.x = bf16_rne(f.x); h.y = bf16_rne(f.y); h.z = bf16_rne(f.z); h.w = bf16_rne(f.w);
        *(ushort4v*)(Wbf + (size_t)o * KHE + k) = h;
    } else if (bid < PREP_ACONV + PREP_WCONV + PREP_CBIAS) {
        int o = (bid - PREP_ACONV - PREP_WCONV) * 4 + (tid >> 6);
        int lane = tid & 63;
        const float* w = W + (size_t)o * 3072 + ND;
        float wr[16];
        #pragma unroll
        for (int j = 0; j < 16; ++j) wr[j] = w[lane + j * 64];
        float bo = bias[o];
        for (int b = 0; b < NB; ++b) {
            const float* cc = c_t + (size_t)b * ND;
            float s = 0.f;
            #pragma unroll
            for (int j = 0; j < 16; ++j) s = fmaf(cc[lane + j * 64], wr[j], s);
            #pragma unroll
            for (int m = 1; m < 64; m <<= 1) s += __shfl_xor(s, m);
            if (lane == 0) cbias[b * NOUT + o] = s + bo;
        }
    } else {
        int idx = (bid - PREP_ACONV - PREP_WCONV - PREP_CBIAS) * 256 + tid;
        ((float4*)logits)[idx] = make_float4(0.f, 0.f, 0.f, 0.f);
    }
}

// ---------- standalone prep pieces (ws-fallback path only) -------------------------------
__global__ __launch_bounds__(256) void wconv_k(const float* __restrict__ W,
                                               unsigned short* __restrict__ Wbf) {
    int idx = blockIdx.x * 256 + threadIdx.x;
    int o = idx >> 9;
    int k = (idx & 511) * 4;
    int off = (k < ND) ? k : (k + ND);
    float4 f = *(const float4*)(W + (size_t)o * 3072 + off);
    ushort4v h;
    h.x = bf16_rne(f.x); h.y = bf16_rne(f.y); h.z = bf16_rne(f.z); h.w = bf16_rne(f.w);
    *(ushort4v*)(Wbf + (size_t)o * KHE + k) = h;
}

__global__ __launch_bounds__(256) void cbias_k(const float* __restrict__ c_t,
                                               const float* __restrict__ W,
                                               const float* __restrict__ bias,
                                               float* __restrict__ cbias) {
    int o = blockIdx.x * 4 + (threadIdx.x >> 6);
    int lane = threadIdx.x & 63;
    const float* w = W + (size_t)o * 3072 + ND;
    float wr[16];
    #pragma unroll
    for (int j = 0; j < 16; ++j) wr[j] = w[lane + j * 64];
    float bo = bias[o];
    for (int b = 0; b < NB; ++b) {
        const float* c = c_t + (size_t)b * ND;
        float s = 0.f;
        #pragma unroll
        for (int j = 0; j < 16; ++j) s = fmaf(c[lane + j * 64], wr[j], s);
        #pragma unroll
        for (int m = 1; m < 64; m <<= 1) s += __shfl_xor(s, m);
        if (lane == 0) cbias[b * NOUT + o] = s + bo;
    }
}

// ---------- GEMM: 256x256, 8 waves (2M x 4N), BK=64, ONE barrier per K-tile --------------
// Per tile, per wave: 8 sub-phases of 8 MFMA in snake order over (mh,nh,ks):
//   (0,0,0)(0,1,0)(1,1,0)(1,0,0)(1,0,1)(1,1,1)(0,1,1)(0,0,1)
// ds_reads (24 b128, the minimum) are all issued by sub-phase 3, each 1-3 sub-phases
// ahead of use -> compiler emits counted lgkmcnt, LDS servicing overlaps MFMA.
// Staging is global->VGPR (issued: A-chunks pre-s0, B-chunks s3) then ds_write_b128 in
// s4..s7 -> full-tile HBM-latency cover, and NO ds_read ever follows a ds_write inside a
// tile (zero alias stalls, no LDS-DMA hazard waits). lgkmcnt(0)+barrier at tile end only:
// each wave's reads of buf[cur] were lgkm-drained before its MFMAs, so the barrier alone
// makes buf overwrite safe.
// LDS swizzle (verified 0-conflict R3/R5): slot s of row r holds global 16B-chunk s^(r&7).
__global__ __launch_bounds__(512, 2) void gemm8_k(const unsigned short* __restrict__ Abf,
                                                  const unsigned short* __restrict__ Wbf,
                                                  const float* __restrict__ cbias,
                                                  const float* __restrict__ v,
                                                  float* __restrict__ logits) {
    __shared__ unsigned short Ls[2][512][B8K] __attribute__((aligned(16)));  // 128 KiB
    __shared__ float rowsum[4][B8M];   // 4 KiB
    __shared__ float cb_s[B8N];
    __shared__ float v_s[B8N];

    const int tid = threadIdx.x;
    const int ntile = blockIdx.x & 3;      // 4 ntiles
    const int mtile = blockIdx.x >> 2;     // 128 mtiles
    const int m0 = mtile * B8M;            // 2048 % 256 == 0 -> no batch straddle
    const int o0 = ntile * B8N;
    const int batch = m0 >> 11;

    if (tid < B8N) {
        cb_s[tid] = cbias[batch * NOUT + o0 + tid];
        v_s[tid] = v[o0 + tid];
    }

    const int wid = tid >> 6;        // 0..7
    const int lane = tid & 63;
    const int wm = (wid & 1) * 128;  // 2 m-waves (per-wave C = 128x64)
    const int wn = (wid >> 1) * 64;  // 4 n-waves
    const int lr = lane >> 3;              // staging row-in-8
    const int lc = (lane & 7) ^ lr;        // pre-swizzled source 16B chunk

    f32x4 acc[8][4] = {};

    // staging: chunk c in 0..7; c<4 = A rows [c*64, c*64+64), c>=4 = B rows likewise.
    auto gload = [&](int c, int kt) -> ushort8v {
        if (c < 4) {
            const int r0 = c * 64 + wid * 8;
            return *(const ushort8v*)(Abf + (size_t)(m0 + r0 + lr) * KHE + kt + lc * 8);
        } else {
            const int r0 = (c - 4) * 64 + wid * 8;
            return *(const ushort8v*)(Wbf + (size_t)(o0 + r0 + lr) * KHE + kt + lc * 8);
        }
    };
    auto swrite = [&](unsigned short* bufp, int c, ushort8v val) {
        const int r0 = ((c < 4) ? c * 64 : 256 + (c - 4) * 64) + wid * 8;
        *(ushort8v*)(bufp + (size_t)(r0 + lr) * B8K + (lane & 7) * 8) = val;
    };
    auto loadAf = [&](const unsigned short* bufp, int mh, int ks, short8* d) {
        const int cb = ks * 4 + (lane >> 4);
        #pragma unroll
        for (int i = 0; i < 4; ++i) {
            const int row = wm + mh * 64 + i * 16 + (lane & 15);
            d[i] = *(const short8*)(bufp + (size_t)row * B8K + (cb ^ (row & 7)) * 8);
        }
    };
    auto loadBf = [&](const unsigned short* bufp, int nh, int ks, short8* d) {
        const int cb = ks * 4 + (lane >> 4);
        #pragma unroll
        for (int j = 0; j < 2; ++j) {
            const int row = 256 + wn + nh * 32 + j * 16 + (lane & 15);
            d[j] = *(const short8*)(bufp + (size_t)row * B8K + (cb ^ (row & 7)) * 8);
        }
    };
    auto mfma8 = [&](int mh, int nh, const short8* a4, const short8* b2) {
        __builtin_amdgcn_s_setprio(1);
        #pragma unroll
        for (int i = 0; i < 4; ++i)
            #pragma unroll
            for (int j = 0; j < 2; ++j)
                acc[mh * 4 + i][nh * 2 + j] = __builtin_amdgcn_mfma_f32_16x16x32_bf16(
                    a4[i], b2[j], acc[mh * 4 + i][nh * 2 + j], 0, 0, 0);
        __builtin_amdgcn_s_setprio(0);
    };

    unsigned short* curp = &Ls[0][0][0];
    unsigned short* nxtp = &Ls[1][0][0];

    // prologue: tile 0 staged through regs (one exposed HBM round-trip per block)
    {
        ushort8v g[8];
        #pragma unroll
        for (int c = 0; c < 8; ++c) g[c] = gload(c, 0);
        #pragma unroll
        for (int c = 0; c < 8; ++c) swrite(curp, c, g[c]);
    }
    asm volatile("s_waitcnt lgkmcnt(0)" ::: "memory");
    __builtin_amdgcn_s_barrier();
    asm volatile("" ::: "memory");

    #pragma unroll 1
    for (int t = 0; t < NT8; ++t) {
        const int kt1 = (t + 1) * B8K;
        const bool pf = (t + 1 < NT8);
        short8 aA[4], aB[4], aC[4], aD[4], bA[2], bB[2], bC[2], bD[2];
        ushort8v g0[4], g1[4];

        // front: next-tile A global loads (HBM, needs ~full-tile cover) + s0 fragments
        if (pf) {
            #pragma unroll
            for (int c = 0; c < 4; ++c) g0[c] = gload(c, kt1);
        }
        loadAf(curp, 0, 0, aA);
        loadBf(curp, 0, 0, bA);
        // s0
        loadBf(curp, 1, 0, bB);
        mfma8(0, 0, aA, bA);
        // s1
        loadAf(curp, 1, 0, aB);
        mfma8(0, 1, aA, bB);
        // s2
        loadAf(curp, 1, 1, aC);
        loadBf(curp, 0, 1, bC);
        mfma8(1, 1, aB, bB);
        // s3: last fragment reads + next-tile B global loads (L2-resident Wbf)
        loadBf(curp, 1, 1, bD);
        loadAf(curp, 0, 1, aD);
        if (pf) {
            #pragma unroll
            for (int c = 0; c < 4; ++c) g1[c] = gload(c + 4, kt1);
        }
        mfma8(1, 0, aB, bA);
        // s4..s7: pure MFMA + staged ds_writes to buf[nxt] (no reads follow -> no alias)
        if (pf) { swrite(nxtp, 0, g0[0]); swrite(nxtp, 1, g0[1]); }
        mfma8(1, 0, aC, bC);
        if (pf) { swrite(nxtp, 2, g0[2]); swrite(nxtp, 3, g0[3]); }
        mfma8(1, 1, aC, bD);
        if (pf) { swrite(nxtp, 4, g1[0]); swrite(nxtp, 5, g1[1]); }
        mfma8(0, 1, aD, bD);
        if (pf) { swrite(nxtp, 6, g1[2]); swrite(nxtp, 7, g1[3]); }
        mfma8(0, 0, aD, bC);

        // tile boundary: drain own LDS ops, then sync. No vmcnt drain needed (plain
        // global loads are consumed via register deps).
        asm volatile("s_waitcnt lgkmcnt(0)" ::: "memory");
        __builtin_amdgcn_s_barrier();
        asm volatile("" ::: "memory");
        unsigned short* tp = curp; curp = nxtp; nxtp = tp;
    }

    __syncthreads();

    // epilogue: relu(acc + cbias) * v, reduce over this block's 256 o's.
    // C/D: col = lane&15 (o), row = (lane>>4)*4 + reg (m).  (verified rounds 1-7)
    const int col = lane & 15;
    const int q = lane >> 4;
    float vv[4], cbv[4];
    #pragma unroll
    for (int j = 0; j < 4; ++j) {
        const int oc = wn + j * 16 + col;
        vv[j] = v_s[oc];
        cbv[j] = cb_s[oc];
    }
    #pragma unroll
    for (int i = 0; i < 8; ++i) {
        #pragma unroll
        for (int r = 0; r < 4; ++r) {
            float s = 0.f;
            #pragma unroll
            for (int j = 0; j < 4; ++j) {
                float e = acc[i][j][r] + cbv[j];
                e = fmaxf(e, 0.f);
                s = fmaf(e, vv[j], s);
            }
            s += __shfl_xor(s, 1);
            s += __shfl_xor(s, 2);
            s += __shfl_xor(s, 4);
            s += __shfl_xor(s, 8);
            if (col == 0) rowsum[wid >> 1][wm + i * 16 + q * 4 + r] = s;
        }
    }
    __syncthreads();
    if (tid < B8M)
        atomicAdd(&logits[m0 + tid],
                  rowsum[0][tid] + rowsum[1][tid] + rowsum[2][tid] + rowsum[3][tid]);
}

// ---------- fallback GEMM (fp32 A staged+converted in-kernel, 128x128, BK=32) ------------
__global__ __launch_bounds__(256) void gemm_att_k(const float* __restrict__ hidden,
                                                  const float* __restrict__ enc,
                                                  const unsigned short* __restrict__ Wbf,
                                                  const float* __restrict__ Wf,
                                                  const float* __restrict__ cbias,
                                                  const float* __restrict__ v,
                                                  float* __restrict__ logits,
                                                  int use_wbf) {
    __shared__ unsigned short As[128 * 32] __attribute__((aligned(16)));
    __shared__ unsigned short Bs[128 * 32] __attribute__((aligned(16)));
    __shared__ float rowsum[2][128];
    __shared__ float cb_s[128];
    __shared__ float v_s[128];

    const int tid = threadIdx.x;
    const int ntile = blockIdx.x & 7;
    const int mtile = blockIdx.x >> 3;
    const int m0 = mtile * 128;
    const int o0 = ntile * 128;
    const int batch = m0 >> 11;

    if (tid < 128) {
        cb_s[tid] = cbias[batch * NOUT + o0 + tid];
        v_s[tid] = v[o0 + tid];
    }

    const int wid = tid >> 6;
    const int lane = tid & 63;
    const int wm = (wid & 1) * 64;
    const int wn = (wid >> 1) * 64;

    f32x4 acc[4][4] = {};

    for (int kt = 0; kt < KHE; kt += 32) {
        const float* Abase = (kt < ND) ? hidden : enc;
        const int aoff = (kt < ND) ? kt : (kt - ND);
        #pragma unroll
        for (int i = 0; i < 4; ++i) {
            int p = tid + i * 256;
            int row = p >> 3, kc = p & 7;
            float4 f = *(const float4*)(Abase + (size_t)(m0 + row) * ND + aoff + kc * 4);
            ushort4v h;
            h.x = bf16_rne(f.x); h.y = bf16_rne(f.y); h.z = bf16_rne(f.z); h.w = bf16_rne(f.w);
            *(ushort4v*)(As + row * 32 + kc * 4) = h;
        }
        if (use_wbf) {
            #pragma unroll
            for (int i = 0; i < 2; ++i) {
                int u = tid + i * 256;
                int ol = u >> 2, kc = u & 3;
                ushort8v w8 = *(const ushort8v*)(Wbf + (size_t)(o0 + ol) * KHE + kt + kc * 8);
                *(ushort8v*)(Bs + ol * 32 + kc * 8) = w8;
            }
        } else {
            const int woff = (kt < ND) ? kt : (kt + ND);
            #pragma unroll
            for (int i = 0; i < 4; ++i) {
                int p = tid + i * 256;
                int row = p >> 3, kc = p & 7;
                float4 f = *(const float4*)(Wf + (size_t)(o0 + row) * 3072 + woff + kc * 4);
                ushort4v h;
                h.x = bf16_rne(f.x); h.y = bf16_rne(f.y); h.z = bf16_rne(f.z); h.w = bf16_rne(f.w);
                *(ushort4v*)(Bs + row * 32 + kc * 4) = h;
            }
        }
        __syncthreads();

        short8 a_frag[4], b_frag[4];
        #pragma unroll
        for (int i = 0; i < 4; ++i)
            a_frag[i] = *(const short8*)(As + (wm + i * 16 + (lane & 15)) * 32 + (lane >> 4) * 8);
        #pragma unroll
        for (int j = 0; j < 4; ++j)
            b_frag[j] = *(const short8*)(Bs + (wn + j * 16 + (lane & 15)) * 32 + (lane >> 4) * 8);
        #pragma unroll
        for (int i = 0; i < 4; ++i)
            #pragma unroll
            for (int j = 0; j < 4; ++j)
                acc[i][j] = __builtin_amdgcn_mfma_f32_16x16x32_bf16(a_frag[i], b_frag[j],
                                                                    acc[i][j], 0, 0, 0);
        __syncthreads();
    }

    const int col = lane & 15;
    const int q = lane >> 4;
    float vv[4], cbv[4];
    #pragma unroll
    for (int j = 0; j < 4; ++j) {
        int oc = wn + j * 16 + col;
        vv[j] = v_s[oc];
        cbv[j] = cb_s[oc];
    }
    #pragma unroll
    for (int i = 0; i < 4; ++i) {
        #pragma unroll
        for (int r = 0; r < 4; ++r) {
            float s = 0.f;
            #pragma unroll
            for (int j = 0; j < 4; ++j) {
                float e = acc[i][j][r] + cbv[j];
                e = fmaxf(e, 0.f);
                s = fmaf(e, vv[j], s);
            }
            s += __shfl_xor(s, 1);
            s += __shfl_xor(s, 2);
            s += __shfl_xor(s, 4);
            s += __shfl_xor(s, 8);
            if (col == 0) rowsum[wid >> 1][wm + i * 16 + q * 4 + r] = s;
        }
    }
    __syncthreads();
    if (tid < 128) atomicAdd(&logits[m0 + tid], rowsum[0][tid] + rowsum[1][tid]);
}

// ---------- softmax over S per batch -----------------------------------------------------
__global__ __launch_bounds__(256) void softmax_k(const float* __restrict__ logits,
                                                 float* __restrict__ out) {
    const int b = blockIdx.x;
    const int tid = threadIdx.x;
    const int lane = tid & 63, wid = tid >> 6;
    __shared__ float redmax[4];
    __shared__ float redsum[4];
    const float* L = logits + (size_t)b * NS;
    float x[8];
    float mx = -3.4e38f;
    #pragma unroll
    for (int i = 0; i < 8; ++i) {
        x[i] = L[tid + i * 256];
        mx = fmaxf(mx, x[i]);
    }
    #pragma unroll
    for (int m = 1; m < 64; m <<= 1) mx = fmaxf(mx, __shfl_xor(mx, m));
    if (lane == 0) redmax[wid] = mx;
    __syncthreads();
    mx = fmaxf(fmaxf(redmax[0], redmax[1]), fmaxf(redmax[2], redmax[3]));
    float sum = 0.f;
    #pragma unroll
    for (int i = 0; i < 8; ++i) {
        x[i] = expf(x[i] - mx);
        sum += x[i];
    }
    #pragma unroll
    for (int m = 1; m < 64; m <<= 1) sum += __shfl_xor(sum, m);
    if (lane == 0) redsum[wid] = sum;
    __syncthreads();
    float inv = 1.0f / (redsum[0] + redsum[1] + redsum[2] + redsum[3]);
    #pragma unroll
    for (int i = 0; i < 8; ++i) out[(size_t)b * NS + tid + i * 256] = x[i] * inv;
}

extern "C" void kernel_launch(void* const* d_in, const int* in_sizes, int n_in,
                              void* d_out, int out_size, void* d_ws, size_t ws_size,
                              hipStream_t stream) {
    const float* hidden = (const float*)d_in[0];
    const float* enc    = (const float*)d_in[1];
    const float* c_t    = (const float*)d_in[2];
    const float* W      = (const float*)d_in[3];
    const float* bias   = (const float*)d_in[4];
    const float* v      = (const float*)d_in[5];
    float* out = (float*)d_out;

    char* ws = (char*)d_ws;
    float* logits = (float*)ws;                             // 131072 B
    float* cbias  = (float*)(ws + 131072);                  //  65536 B
    unsigned short* Wbf = (unsigned short*)(ws + 196608);   // 4 MiB
    unsigned short* Abf = (unsigned short*)(ws + 196608 + 4194304);  // 128 MiB
    const size_t need_wbf = 196608 + (size_t)NOUT * KHE * 2;
    const size_t need_abf = need_wbf + (size_t)NM * KHE * 2;

    if (ws_size >= need_abf) {
        prep_k<<<PREP_ACONV + PREP_WCONV + PREP_CBIAS + PREP_ZERO, 256, 0, stream>>>(
            hidden, enc, c_t, W, bias, Abf, Wbf, cbias, logits);
        gemm8_k<<<(NM / B8M) * (NOUT / B8N), 512, 0, stream>>>(Abf, Wbf, cbias, v, logits);
    } else if (ws_size >= need_wbf) {
        hipMemsetAsync(logits, 0, NM * sizeof(float), stream);
        cbias_k<<<NOUT / 4, 256, 0, stream>>>(c_t, W, bias, cbias);
        wconv_k<<<(NOUT * KHE / 4) / 256, 256, 0, stream>>>(W, Wbf);
        gemm_att_k<<<(NM / 128) * (NOUT / 128), 256, 0, stream>>>(hidden, enc, Wbf, W, cbias, v,
                                                                  logits, 1);
    } else {
        hipMemsetAsync(logits, 0, NM * sizeof(float), stream);
        cbias_k<<<NOUT / 4, 256, 0, stream>>>(c_t, W, bias, cbias);
        gemm_att_k<<<(NM / 128) * (NOUT / 128), 256, 0, stream>>>(hidden, enc, Wbf, W, cbias, v,
                                                                  logits, 0);
    }
    softmax_k<<<NB, 256, 0, stream>>>(logits, out);
}